// Round 11
// baseline (164.646 us; speedup 1.0000x reference)
//
#include <hip/hip_runtime.h>

#define BB 32
#define NN 256
#define EE 300
#define HH 256
#define KK 8
#define MARGINF 0.2f
#define EP 320   // E padded for K-loop

typedef __attribute__((ext_vector_type(8))) short bf16x8;
typedef __attribute__((ext_vector_type(8))) _Float16 f16x8;
typedef __attribute__((ext_vector_type(4))) float f32x4;
typedef __attribute__((ext_vector_type(16))) float f32x16;

__device__ inline ushort f2bf(float f) {
  unsigned u = __float_as_uint(f);
  u += 0x7fffu + ((u >> 16) & 1u);          // RNE
  return (ushort)(u >> 16);
}
__device__ inline unsigned pack2bf(float f0, float f1) {   // [f0 lo | f1 hi], RNE
  unsigned u0 = __float_as_uint(f0); u0 += 0x7fffu + ((u0 >> 16) & 1u);
  unsigned u1 = __float_as_uint(f1); u1 += 0x7fffu + ((u1 >> 16) & 1u);
  return (u0 >> 16) | (u1 & 0xffff0000u);
}

// ---------------------------------------------------------------------------
// wconv: W fp32 -> bf16 [2][256][320] (zero-padded) + zero numden[1024]
// ---------------------------------------------------------------------------
__global__ __launch_bounds__(256) void wconv_kernel(
    const float* __restrict__ Wa, const float* __restrict__ Wc,
    ushort* __restrict__ Wb, float* __restrict__ numden)
{
  if (blockIdx.x == 640) {
    const int t = threadIdx.x;
#pragma unroll
    for (int i = 0; i < 4; i++) numden[t * 4 + i] = 0.f;
    return;
  }
  const int i = blockIdx.x * 256 + threadIdx.x;   // over 2*256*320 = 163840
  const int e = i % EP;
  const int hw = i / EP;
  const int h = hw & 255;
  const int w = hw >> 8;
  const float* src = w ? Wc : Wa;
  Wb[i] = (e < EE) ? f2bf(src[(size_t)h * EE + e]) : (ushort)0;
}

// ---------------------------------------------------------------------------
// proj v3: 16-row n-tiles, grid (16, 96) = 1536 WGs -> 6 WGs/CU (6 waves/
// SIMD of latency hiding). X tile staged once (X read exactly once
// globally); W B-frags straight from L2-hot bf16 Wb; MFMA 16x16x32 bf16
// (operand/C layout validated rounds 5-10). Emits fp16 AT.
// ---------------------------------------------------------------------------
__global__ __launch_bounds__(256, 6) void proj_kernel(
    const float* __restrict__ he_a, const float* __restrict__ he_p,
    const float* __restrict__ he_n, const ushort* __restrict__ Wb,
    const float* __restrict__ b_a2h, const float* __restrict__ b_c2h,
    _Float16* __restrict__ AT)
{
  const int z = blockIdx.y;           // 96 = 3*BB
  const int which = z >> 5;
  const int b = z & 31;
  const int n0 = blockIdx.x * 16;
  const int tid = threadIdx.x;
  const int wv = tid >> 6;
  const int lane = tid & 63;
  const int col = lane & 15;
  const int quad = lane >> 4;

  const float* X = (which == 0 ? he_a : which == 1 ? he_p : he_n) + (size_t)b * NN * EE;
  const ushort* W = Wb + (size_t)(which == 0 ? 0 : 1) * HH * EP;
  const float* bias = (which == 0 ? b_a2h : b_c2h);

  __shared__ __align__(16) ushort sX[16][328];   // [n_local][e] bf16
  __shared__ __align__(16) _Float16 tr[16][264]; // [n_local][h] epilogue

  {  // stage X: 16 rows x 320 bf16; 16 thr/row, 5 float4 each
    const int row = tid >> 4, seg = tid & 15;
    const float* xr = X + (size_t)(n0 + row) * EE;
#pragma unroll
    for (int q = 0; q < 5; q++) {
      const int j = seg + 16 * q;          // float4 slot 0..79 (75 valid)
      float4 xv = {0.f, 0.f, 0.f, 0.f};
      if (j < 75) xv = *(const float4*)&xr[4 * j];
      uint2 p; p.x = pack2bf(xv.x, xv.y); p.y = pack2bf(xv.z, xv.w);
      *(uint2*)&sX[row][4 * j] = p;
    }
  }
  __syncthreads();

  f32x4 acc[4];
#pragma unroll
  for (int mb = 0; mb < 4; mb++) acc[mb] = (f32x4){0.f, 0.f, 0.f, 0.f};

#pragma unroll
  for (int ks = 0; ks < 10; ks++) {
    const int off = 32 * ks + 8 * quad;
    const bf16x8 a0 = *(const bf16x8*)&sX[col][off];
#pragma unroll
    for (int mb = 0; mb < 4; mb++) {
      const bf16x8 w8 = *(const bf16x8*)&W[(size_t)(64 * wv + 16 * mb + col) * EP + off];
      acc[mb] = __builtin_amdgcn_mfma_f32_16x16x32_bf16(a0, w8, acc[mb], 0, 0, 0);
    }
  }

  // epilogue: +bias, fp16, transpose through LDS, coalesced store
#pragma unroll
  for (int mb = 0; mb < 4; mb++) {
    const float bi = bias[64 * wv + 16 * mb + col];
#pragma unroll
    for (int r = 0; r < 4; r++)
      tr[4 * quad + r][64 * wv + 16 * mb + col] = (_Float16)(acc[mb][r] + bi);
  }
  __syncthreads();
  {  // 16 rows x 512 B: 16 thr/row, 2 uint4 each
    const int row = tid >> 4, seg = tid & 15;
    _Float16* dst = &AT[((size_t)(which * BB + b) * NN + n0 + row) * HH];
    *(uint4*)&dst[seg * 16]     = *(const uint4*)&tr[row][seg * 16];
    *(uint4*)&dst[seg * 16 + 8] = *(const uint4*)&tr[row][seg * 16 + 8];
  }
}

// ---------------------------------------------------------------------------
// attn v6: one WG per (which,b,n-quarter,m-half), all 8 heads fused.
// Stages 128 Ac rows (74 KB LDS incl. weights) -> 2 WGs/CU, 2 waves/SIMD.
// Single barrier, then the k-loop free-runs. Wave roles: strip=wv&1 (32
// n-rows of the quarter), mq=wv>>1 (64 m-rows of the staged half).
// A-packs v_pk_mul_f16 from L1-resident Aa strip; B from LDS; 32x32x16 f16
// MFMA; exp+reduce; per-(g,k) num/den via device-scope atomicAdd (numden
// zeroed by wconv). Register shape identical to the r10 no-spill kernel.
// blockIdx = t*64 + g -> idx%8 = g%8 (replicas of (which,b) on one XCD).
// ---------------------------------------------------------------------------
__global__ __launch_bounds__(256, 2) void attn_kernel(
    const _Float16* __restrict__ AT, const float* __restrict__ Watt,
    const float* __restrict__ Wfc, float* __restrict__ numden)
{
  const int idx = blockIdx.x;        // t*64 + g, t = q*2 + mh
  const int t = idx >> 6;
  const int q = t >> 1;
  const int mh = t & 1;
  const int g = idx & 63;
  const int which = g >> 5;
  const int b = g & 31;
  const int tid = threadIdx.x;
  const int wv = tid >> 6;
  const int lane = tid & 63;
  const int row32 = lane & 31;
  const int half32 = lane >> 5;
  const int strip = wv & 1;
  const int mq = wv >> 1;

  const _Float16* At_a = AT + (size_t)b * NN * HH;                       // anchor [n][h]
  const _Float16* At_c = AT + ((size_t)(1 + which) * BB + b) * NN * HH;  // pos/neg [m][h]
  const uint4* Ac_u4 = (const uint4*)At_c;

  __shared__ __align__(16) _Float16 sAc[128][264];   // 67.6 KB (m-half)
  __shared__ __align__(16) _Float16 wkh[8][256];
  __shared__ __align__(16) _Float16 wfh[8][256];

  // ---- stage: 128 Ac rows (4096 uint4, 16/thread) + weight rows
  const int srow = tid >> 5, scol8 = (tid & 31) * 8;
#pragma unroll
  for (int tt = 0; tt < 16; tt++)
    *(uint4*)&sAc[8 * tt + srow][scol8] =
        Ac_u4[(size_t)(128 * mh + 8 * tt + srow) * 32 + (tid & 31)];
#pragma unroll
  for (int kk = 0; kk < KK; kk++) {
    wkh[kk][tid] = (_Float16)Watt[kk * HH + tid];
    wfh[kk][tid] = (_Float16)Wfc[kk * HH + tid];
  }
  __syncthreads();   // the ONLY barrier

  const int nbase = 64 * q + 32 * strip;
  const _Float16* arow = At_a + (size_t)(nbase + row32) * HH;  // L1-resident

#pragma unroll 1
  for (int kk = 0; kk < KK; kk++) {
    // A-frags for this head: (wk .* Aa) and (wfc .* Aa), K=256
    f16x8 saf[16], gaf[16];
#pragma unroll
    for (int ks = 0; ks < 16; ks++) {
      const int off = 16 * ks + 8 * half32;
      const f16x8 a = *(const f16x8*)&arow[off];
      const f16x8 w = *(const f16x8*)&wkh[kk][off];
      const f16x8 f = *(const f16x8*)&wfh[kk][off];
      saf[ks] = a * w;                 // v_pk_mul_f16 x4
      gaf[ks] = a * f;
    }

    f32x16 aS0 = {0,0,0,0,0,0,0,0,0,0,0,0,0,0,0,0};
    f32x16 aS1 = {0,0,0,0,0,0,0,0,0,0,0,0,0,0,0,0};
    f32x16 aG0 = {0,0,0,0,0,0,0,0,0,0,0,0,0,0,0,0};
    f32x16 aG1 = {0,0,0,0,0,0,0,0,0,0,0,0,0,0,0,0};
#pragma unroll
    for (int ks = 0; ks < 16; ks++) {
      const int off = 16 * ks + 8 * half32;
      const f16x8 b0 = *(const f16x8*)&sAc[64 * mq + row32][off];
      const f16x8 b1 = *(const f16x8*)&sAc[64 * mq + 32 + row32][off];
      aS0 = __builtin_amdgcn_mfma_f32_32x32x16_f16(saf[ks], b0, aS0, 0, 0, 0);
      aG0 = __builtin_amdgcn_mfma_f32_32x32x16_f16(gaf[ks], b0, aG0, 0, 0, 0);
      aS1 = __builtin_amdgcn_mfma_f32_32x32x16_f16(saf[ks], b1, aS1, 0, 0, 0);
      aG1 = __builtin_amdgcn_mfma_f32_32x32x16_f16(gaf[ks], b1, aG1, 0, 0, 0);
    }

    float num = 0.f, den = 0.f;
#pragma unroll
    for (int r = 0; r < 16; r++) {
      const float p0 = __expf(aS0[r]);
      den += p0; num += p0 * aG0[r];
      const float p1 = __expf(aS1[r]);
      den += p1; num += p1 * aG1[r];
    }

    // wave butterfly, then one atomic pair per wave
#pragma unroll
    for (int off = 32; off >= 1; off >>= 1) {
      num += __shfl_xor(num, off);
      den += __shfl_xor(den, off);
    }
    if (lane == 0) {
      atomicAdd(&numden[(g * KK + kk) * 2 + 0], num);
      atomicAdd(&numden[(g * KK + kk) * 2 + 1], den);
    }
  }
}

// ---------------------------------------------------------------------------
// loss: score(g) = b_fc + sum_k num[g,k]/den[g,k];  mean_b relu(sn-sp+margin)
// ---------------------------------------------------------------------------
__global__ __launch_bounds__(64) void loss_kernel(
    const float* __restrict__ numden, const float* __restrict__ bfc,
    float* __restrict__ out)
{
  const int tid = threadIdx.x;    // tid = g = which*32 + b
  float s = bfc[0];
#pragma unroll
  for (int k = 0; k < KK; k++)
    s += numden[(tid * KK + k) * 2] / numden[(tid * KK + k) * 2 + 1];
  const float other = __shfl(s, tid + 32);
  float v = 0.f;
  if (tid < 32) v = fmaxf(other - s + MARGINF, 0.f);
#pragma unroll
  for (int off = 32; off >= 1; off >>= 1) v += __shfl_xor(v, off);
  if (tid == 0) out[0] = v * (1.0f / 32.0f);
}

// ---------------------------------------------------------------------------
extern "C" void kernel_launch(void* const* d_in, const int* in_sizes, int n_in,
                              void* d_out, int out_size, void* d_ws, size_t ws_size,
                              hipStream_t stream) {
  const float* he_a  = (const float*)d_in[0];
  const float* he_p  = (const float*)d_in[1];
  const float* he_n  = (const float*)d_in[2];
  const float* W_a2h = (const float*)d_in[3];
  const float* b_a2h = (const float*)d_in[4];
  const float* W_c2h = (const float*)d_in[5];
  const float* b_c2h = (const float*)d_in[6];
  const float* W_att = (const float*)d_in[7];
  // d_in[8] = b_att: cancels in global softmax
  const float* W_fc  = (const float*)d_in[9];
  const float* b_fc  = (const float*)d_in[10];

  _Float16* AT = (_Float16*)d_ws;                            // [3][B][N][H] fp16, 12.6 MB
  ushort* Wb = (ushort*)(AT + (size_t)3 * BB * NN * HH);     // [2][256][320] bf16, 320 KB
  float* numden = (float*)(Wb + (size_t)2 * HH * EP);        // [64][8][2] fp32, 4 KB
  (void)ws_size; (void)in_sizes; (void)n_in; (void)out_size;

  wconv_kernel<<<641, 256, 0, stream>>>(W_a2h, W_c2h, Wb, numden);
  dim3 pg(16, 96);
  proj_kernel<<<pg, 256, 0, stream>>>(he_a, he_p, he_n, Wb, b_a2h, b_c2h, AT);
  attn_kernel<<<512, 256, 0, stream>>>(AT, W_att, W_fc, numden);
  loss_kernel<<<1, 64, 0, stream>>>(numden, b_fc, (float*)d_out);
}